// Round 2
// baseline (75493.304 us; speedup 1.0000x reference)
//
#include <hip/hip_runtime.h>

static constexpr int BB = 16;     // batches
static constexpr int NN = 325;    // nodes
static constexpr int DD = 64;     // channels
static constexpr int HH = 4;      // heads
static constexpr int SEQ = 12;
static constexpr int MAXDEG = 96; // binom(325,0.1): mean 33.5, sigma 5.4 -> 96 is >10 sigma
static constexpr int NW = 16;     // waves per block
static constexpr int MAXK = 21;   // ceil(325/16) nodes per wave
static constexpr float DT = 0.1f;
static constexpr float NEG = 0.2f;
static constexpr float THRESH = 0.9f;

__device__ __forceinline__ float groupmax16(float v) {
#pragma unroll
  for (int mm = 1; mm < 16; mm <<= 1) v = fmaxf(v, __shfl_xor(v, mm, 64));
  return v;
}
__device__ __forceinline__ float groupsum16(float v) {
#pragma unroll
  for (int mm = 1; mm < 16; mm <<= 1) v += __shfl_xor(v, mm, 64);
  return v;
}

// Sparse softmax-attention for node n, everything LDS-resident.
// Each of the 16 lanes in a head group owns one neighbor per chunk: computes
// its exp ONCE, then weights are shuffle-broadcast for the aggregation fmas.
__device__ __forceinline__ float attn_lds(const float* __restrict__ slab,
                                          const float* __restrict__ ses,
                                          const float* __restrict__ sed,
                                          const unsigned short* __restrict__ cl,
                                          int dg, int n, int lane, int head, int hd) {
  const float esi = ses[n * HH + head];
  const int nch = (dg + 15) >> 4;
  // pass 1: per-head row max
  float m = -1e30f;
  for (int c = 0; c < nch; ++c) {
    int q = c * 16 + hd;
    if (q < dg) {
      int j = cl[q];
      float e = esi + sed[j * HH + head];
      e = fmaxf(e, NEG * e);  // leaky_relu
      m = fmaxf(m, e);
    }
  }
  m = groupmax16(m);
  // pass 2: weights + aggregation
  float denp = 0.f, av = 0.f;
  const int base = lane & 48;  // head-group base lane
  for (int c = 0; c < nch; ++c) {
    int q = c * 16 + hd;
    int j;
    float w;
    if (q < dg) {
      j = cl[q];
      float e = esi + sed[j * HH + head];
      e = fmaxf(e, NEG * e);
      w = __expf(e - m);
    } else {
      j = n;
      w = 0.f;
    }
    denp += w;
    int cnt = dg - c * 16;
    cnt = cnt < 16 ? cnt : 16;
    for (int jj = 0; jj < cnt; ++jj) {
      float wj = __shfl(w, base + jj, 64);
      int jx = __shfl(j, base + jj, 64);
      av = fmaf(wj, slab[jx * DD + lane], av);
    }
  }
  float den = groupsum16(denp);
  return av / den;
}

// 4-node batched matvec: ho[u][lane] = sum_d xv[u][d] * M[d][lane].
// Shares the 16KB weight stream across 4 nodes; x broadcast via b128 LDS reads.
__device__ __forceinline__ void matvec4(const float* __restrict__ sM, float (*xw)[DD],
                                        const float* xv, int g, int lane, float* ho) {
#pragma unroll
  for (int u = 0; u < 4; ++u)
    if (u < g) xw[u][lane] = xv[u];
  __threadfence_block();
  float a0 = 0.f, a1 = 0.f, a2 = 0.f, a3 = 0.f;
#pragma unroll
  for (int d4 = 0; d4 < 16; ++d4) {
    float4 x0 = ((const float4*)xw[0])[d4];
    float4 x1 = ((const float4*)xw[1])[d4];
    float4 x2 = ((const float4*)xw[2])[d4];
    float4 x3 = ((const float4*)xw[3])[d4];
    const float* wp = sM + d4 * 4 * DD + lane;
    float w0 = wp[0], w1 = wp[DD], w2 = wp[2 * DD], w3 = wp[3 * DD];
    a0 = fmaf(x0.w, w3, fmaf(x0.z, w2, fmaf(x0.y, w1, fmaf(x0.x, w0, a0))));
    a1 = fmaf(x1.w, w3, fmaf(x1.z, w2, fmaf(x1.y, w1, fmaf(x1.x, w0, a1))));
    a2 = fmaf(x2.w, w3, fmaf(x2.z, w2, fmaf(x2.y, w1, fmaf(x2.x, w0, a2))));
    a3 = fmaf(x3.w, w3, fmaf(x3.z, w2, fmaf(x3.y, w1, fmaf(x3.x, w0, a3))));
  }
  __threadfence_block();
  ho[0] = a0; ho[1] = a1; ho[2] = a2; ho[3] = a3;
}

// Same but weights streamed from global (head W1: used only 13x per run).
__device__ __forceinline__ void matvec4g(const float* __restrict__ gM, float (*xw)[DD],
                                         const float* xv, int g, int lane, float* ho) {
#pragma unroll
  for (int u = 0; u < 4; ++u)
    if (u < g) xw[u][lane] = xv[u];
  __threadfence_block();
  float a0 = 0.f, a1 = 0.f, a2 = 0.f, a3 = 0.f;
#pragma unroll
  for (int d4 = 0; d4 < 16; ++d4) {
    float4 x0 = ((const float4*)xw[0])[d4];
    float4 x1 = ((const float4*)xw[1])[d4];
    float4 x2 = ((const float4*)xw[2])[d4];
    float4 x3 = ((const float4*)xw[3])[d4];
    const float* wp = gM + d4 * 4 * DD + lane;
    float w0 = wp[0], w1 = wp[DD], w2 = wp[2 * DD], w3 = wp[3 * DD];
    a0 = fmaf(x0.w, w3, fmaf(x0.z, w2, fmaf(x0.y, w1, fmaf(x0.x, w0, a0))));
    a1 = fmaf(x1.w, w3, fmaf(x1.z, w2, fmaf(x1.y, w1, fmaf(x1.x, w0, a1))));
    a2 = fmaf(x2.w, w3, fmaf(x2.z, w2, fmaf(x2.y, w1, fmaf(x2.x, w0, a2))));
    a3 = fmaf(x3.w, w3, fmaf(x3.z, w2, fmaf(x3.y, w1, fmaf(x3.x, w0, a3))));
  }
  __threadfence_block();
  ho[0] = a0; ho[1] = a1; ho[2] = a2; ho[3] = a3;
}

__device__ __forceinline__ void esed_write(float h, const float* __restrict__ sa,
                                           const float* __restrict__ sd,
                                           float* __restrict__ ses, float* __restrict__ sed,
                                           int n, int head, int hd) {
  float p = h * sa[head * 16 + hd];
  float q = h * sd[head * 16 + hd];
  p = groupsum16(p);
  q = groupsum16(q);
  if (hd == 0) {
    ses[n * HH + head] = p;
    sed[n * HH + head] = q;
  }
}

// One block = one batch. All node-state in LDS; sync via __syncthreads only.
__global__ __launch_bounds__(1024) void ode_kernel(
    const float* __restrict__ y0, const float* __restrict__ graph,
    const float* __restrict__ Wg, const float* __restrict__ a_src,
    const float* __restrict__ a_dst, const float* __restrict__ W1,
    const float* __restrict__ b1, const float* __restrict__ W2,
    const float* __restrict__ b2, float* __restrict__ out,
    unsigned short* __restrict__ colsg, float* __restrict__ yyg,
    float* __restrict__ accg) {
  __shared__ float sW0[64 * 64];     // 16 KB
  __shared__ float sW1g[64 * 64];    // 16 KB
  __shared__ float slab[NN * DD];    // 81.25 KB  h ping-pong slab
  __shared__ float ses[NN * HH];     // 5.08 KB
  __shared__ float sed[NN * HH];     // 5.08 KB
  __shared__ float sasrc[2][64], sadst[2][64];
  __shared__ float sb1[64], sW2l[64];
  __shared__ float xbuf[NW][4][DD];  // 16 KB broadcast rows
  // total ~141 KB <= 160 KB addressable on gfx950

  const int tid = threadIdx.x;
  const int lane = tid & 63;
  const int wv = tid >> 6;
  const int head = lane >> 4;
  const int hd = lane & 15;
  const int b = blockIdx.x;
  float (*xw)[DD] = xbuf[wv];

  // stage shared weights
  for (int i = tid; i < 64 * 64; i += 1024) {
    sW0[i] = Wg[i];
    sW1g[i] = Wg[64 * 64 + i];
  }
  if (tid < 64) {
    sb1[tid] = b1[tid];
    sW2l[tid] = W2[tid];
  }
  if (tid < 128) {
    sasrc[tid >> 6][tid & 63] = a_src[tid];
    sadst[tid >> 6][tid & 63] = a_dst[tid];
  }

  // adjacency for this wave's own nodes (ballot compaction, u16 cols in ws)
  int degreg[MAXK];
  int nmine = 0;
  for (int k = 0; k < MAXK; ++k) {
    int n = wv + NW * k;
    if (n >= NN) break;
    nmine = k + 1;
    unsigned short* cr = colsg + ((size_t)b * NN + n) * MAXDEG;
    int dc = 0;
    for (int basej = 0; basej < NN; basej += 64) {
      int j = basej + lane;
      bool pred = (j < NN) && ((graph[(size_t)n * NN + j] > THRESH) || (j == n));
      unsigned long long mk = __ballot(pred);
      int pos = dc + (int)__popcll(mk & ((1ULL << lane) - 1ULL));
      if (pred && pos < MAXDEG) cr[pos] = (unsigned short)j;
      dc += (int)__popcll(mk);
    }
    degreg[k] = dc < MAXDEG ? dc : MAXDEG;
  }

  // initial state: yy = y0, slab = W0*y0, scores, head output at t=0
  for (int k0 = 0; k0 < nmine; k0 += 4) {
    int g = nmine - k0;
    g = g < 4 ? g : 4;
    float yv[4], ho[4];
#pragma unroll
    for (int u = 0; u < 4; ++u)
      if (u < g) {
        int n = wv + NW * (k0 + u);
        size_t idx = ((size_t)b * NN + n) * DD + lane;
        yv[u] = y0[idx];
        yyg[idx] = yv[u];
      }
    matvec4(sW0, xw, yv, g, lane, ho);
#pragma unroll
    for (int u = 0; u < 4; ++u)
      if (u < g) {
        int n = wv + NW * (k0 + u);
        slab[n * DD + lane] = ho[u];
        esed_write(ho[u], sasrc[0], sadst[0], ses, sed, n, head, hd);
      }
    matvec4g(W1, xw, yv, g, lane, ho);
#pragma unroll
    for (int u = 0; u < 4; ++u)
      if (u < g) {
        int n = wv + NW * (k0 + u);
        float o = tanhf(ho[u] + sb1[lane]) * sW2l[lane];
#pragma unroll
        for (int mm = 1; mm < 64; mm <<= 1) o += __shfl_xor(o, mm, 64);
        if (lane == 0) out[((size_t)b * (SEQ + 1) + 0) * NN + n] = o + b2[0];
      }
  }
  __syncthreads();

  float xreg[MAXK];  // aggregation results between halves (scratch-backed is fine)

  for (int t = 0; t < SEQ; ++t) {
    for (int s = 0; s < 4; ++s) {
      // ===== layer-0 eval: read-half (aggregate slab=h1) =====
      for (int k = 0; k < nmine; ++k) {
        int n = wv + NW * k;
        xreg[k] = attn_lds(slab, ses, sed, colsg + ((size_t)b * NN + n) * MAXDEG,
                           degreg[k], n, lane, head, hd);
      }
      __syncthreads();
      // write-half: elu -> W1g -> slab=h2, layer-1 scores
      for (int k0 = 0; k0 < nmine; k0 += 4) {
        int g = nmine - k0;
        g = g < 4 ? g : 4;
        float xe[4], ho[4];
#pragma unroll
        for (int u = 0; u < 4; ++u)
          if (u < g) {
            float x = xreg[k0 + u];
            xe[u] = x > 0.f ? x : __expf(x) - 1.f;  // elu (exp2-based ok: e^x = exp)
          }
        matvec4(sW1g, xw, xe, g, lane, ho);
#pragma unroll
        for (int u = 0; u < 4; ++u)
          if (u < g) {
            int n = wv + NW * (k0 + u);
            slab[n * DD + lane] = ho[u];
            esed_write(ho[u], sasrc[1], sadst[1], ses, sed, n, head, hd);
          }
      }
      __syncthreads();

      // ===== layer-1 eval: read-half (aggregate slab=h2 -> k_s) =====
      for (int k = 0; k < nmine; ++k) {
        int n = wv + NW * k;
        xreg[k] = attn_lds(slab, ses, sed, colsg + ((size_t)b * NN + n) * MAXDEG,
                           degreg[k], n, lane, head, hd);
      }
      __syncthreads();
      // write-half: RK bookkeeping -> W0 -> slab=h1(next stage), layer-0 scores
      for (int k0 = 0; k0 < nmine; k0 += 4) {
        int g = nmine - k0;
        g = g < 4 ? g : 4;
        float xn[4], yn[4], ho[4];
#pragma unroll
        for (int u = 0; u < 4; ++u)
          if (u < g) {
            int n = wv + NW * (k0 + u);
            size_t idx = ((size_t)b * NN + n) * DD + lane;
            float kk = xreg[k0 + u];
            float yv = yyg[idx];
            if (s == 0) {
              accg[idx] = kk;
              xn[u] = yv + 0.5f * DT * kk;
            } else if (s == 1) {
              accg[idx] += 2.f * kk;
              xn[u] = yv + 0.5f * DT * kk;
            } else if (s == 2) {
              accg[idx] += 2.f * kk;
              xn[u] = yv + DT * kk;
            } else {
              float a4 = accg[idx] + kk;
              float y1 = yv + (DT / 6.f) * a4;
              yyg[idx] = y1;
              yn[u] = y1;
              xn[u] = y1;
            }
          }
        matvec4(sW0, xw, xn, g, lane, ho);
#pragma unroll
        for (int u = 0; u < 4; ++u)
          if (u < g) {
            int n = wv + NW * (k0 + u);
            slab[n * DD + lane] = ho[u];
            esed_write(ho[u], sasrc[0], sadst[0], ses, sed, n, head, hd);
          }
        if (s == 3) {  // head MLP on fresh y_{t+1}
          matvec4g(W1, xw, yn, g, lane, ho);
#pragma unroll
          for (int u = 0; u < 4; ++u)
            if (u < g) {
              int n = wv + NW * (k0 + u);
              float o = tanhf(ho[u] + sb1[lane]) * sW2l[lane];
#pragma unroll
              for (int mm = 1; mm < 64; mm <<= 1) o += __shfl_xor(o, mm, 64);
              if (lane == 0) out[((size_t)b * (SEQ + 1) + (t + 1)) * NN + n] = o + b2[0];
            }
        }
      }
      __syncthreads();
    }
  }
}

extern "C" void kernel_launch(void* const* d_in, const int* in_sizes, int n_in,
                              void* d_out, int out_size, void* d_ws, size_t ws_size,
                              hipStream_t stream) {
  const float* y0 = (const float*)d_in[0];
  const float* graph = (const float*)d_in[1];
  const float* Wg = (const float*)d_in[2];
  const float* a_src = (const float*)d_in[3];
  const float* a_dst = (const float*)d_in[4];
  const float* W1 = (const float*)d_in[5];
  const float* b1 = (const float*)d_in[6];
  const float* W2 = (const float*)d_in[7];
  const float* b2 = (const float*)d_in[8];
  float* out = (float*)d_out;

  char* ws = (char*)d_ws;
  size_t off = 0;
  auto take = [&](size_t bytes) -> char* {
    char* p = ws + off;
    off += (bytes + 255) & ~size_t(255);
    return p;
  };
  unsigned short* colsg = (unsigned short*)take((size_t)BB * NN * MAXDEG * sizeof(unsigned short));
  float* yyg = (float*)take((size_t)BB * NN * DD * sizeof(float));
  float* accg = (float*)take((size_t)BB * NN * DD * sizeof(float));
  if (off > ws_size) return;  // loud failure: output stays poisoned

  ode_kernel<<<dim3(BB), dim3(1024), 0, stream>>>(y0, graph, Wg, a_src, a_dst, W1, b1,
                                                  W2, b2, out, colsg, yyg, accg);
}

// Round 3
// 1462.670 us; speedup vs baseline: 51.6134x; 51.6134x over previous
//
#include <hip/hip_runtime.h>

static constexpr int BB = 16;      // batches
static constexpr int NN = 325;     // nodes
static constexpr int DD = 64;      // channels
static constexpr int SEQ = 12;
static constexpr int MAXDEG = 80;  // per-row cap: Binom(324,0.1) mean 32.4, sd 5.4 -> 8.8 sigma
static constexpr int NPB = 21;     // nodes per block (16 chunks: 16*21=336 >= 325)
static constexpr int SLDS = 68;    // padded slab row stride (dwords); 68*4=272B = 17*16B (float4-aligned)
static constexpr float DT = 0.1f;
static constexpr float NEG = 0.2f;
static constexpr float THRESH = 0.9f;

__device__ __forceinline__ float rdl(float v, int sl) {
  return __int_as_float(__builtin_amdgcn_readlane(__float_as_int(v), sl));
}

// ---- adjacency build: one wave per row, ballot compaction into padded u16 list
__global__ __launch_bounds__(64) void adj_k(const float* __restrict__ graph,
                                            int* __restrict__ deg,
                                            unsigned short* __restrict__ cols) {
  const int r = blockIdx.x;
  const int lane = threadIdx.x;
  int dc = 0;
  for (int base = 0; base < NN; base += 64) {
    int j = base + lane;
    bool pred = (j < NN) && ((graph[(size_t)r * NN + j] > THRESH) || (j == r));
    unsigned long long mk = __ballot(pred);
    int pos = dc + (int)__popcll(mk & ((1ULL << lane) - 1ULL));
    if (pred && pos < MAXDEG) cols[(size_t)r * MAXDEG + pos] = (unsigned short)j;
    dc += (int)__popcll(mk);
  }
  if (lane == 0) deg[r] = dc;
}

// ---- init: yy=y0, hA = y0@W0, layer-0 scores, head output at t=0
__global__ __launch_bounds__(512) void init_k(
    const float* __restrict__ y0, const float* __restrict__ W0,
    const float* __restrict__ asv, const float* __restrict__ adv,
    const float* __restrict__ Wh, const float* __restrict__ b1v,
    const float* __restrict__ W2v, const float* __restrict__ b2v,
    float* __restrict__ yy, float* __restrict__ hA,
    float* __restrict__ es0, float* __restrict__ ed0, float* __restrict__ out) {
  const int tid = threadIdx.x, lane = tid & 63, wv = tid >> 6;
  const int q = lane & 15, u = lane >> 4;
  const int batch = blockIdx.x & 15, chunk = blockIdx.x >> 4;
  const int n0 = chunk * NPB;
  const int cnt = (NN - n0) < NPB ? (NN - n0) : NPB;
  const int il = wv * 4 + u;
  const int i = n0 + il;
  const bool active = il < cnt;

  float4 x4 = {0.f, 0.f, 0.f, 0.f};
  if (active) {
    x4 = *(const float4*)(y0 + ((size_t)batch * NN + i) * DD + q * 4);
    *(float4*)(yy + ((size_t)batch * NN + i) * DD + q * 4) = x4;
  }

  float wreg[64];
#pragma unroll
  for (int d = 0; d < 64; ++d) wreg[d] = W0[d * 64 + lane];
  float asl = asv[lane], adl = adv[lane];
#pragma unroll
  for (int u2 = 0; u2 < 4; ++u2) {
    int i2l = wv * 4 + u2;
    if (i2l < cnt) {
      int i2 = n0 + i2l;
      float o = 0.f;
#pragma unroll
      for (int dq = 0; dq < 16; ++dq) {
        int sl = (u2 << 4) + dq;
        o = fmaf(rdl(x4.x, sl), wreg[4 * dq + 0], o);
        o = fmaf(rdl(x4.y, sl), wreg[4 * dq + 1], o);
        o = fmaf(rdl(x4.z, sl), wreg[4 * dq + 2], o);
        o = fmaf(rdl(x4.w, sl), wreg[4 * dq + 3], o);
      }
      hA[((size_t)batch * NN + i2) * DD + lane] = o;
      float p = o * asl, qd = o * adl;
#pragma unroll
      for (int mm = 1; mm < 16; mm <<= 1) {
        p += __shfl_xor(p, mm, 64);
        qd += __shfl_xor(qd, mm, 64);
      }
      if ((lane & 15) == 0) {
        es0[((size_t)batch * NN + i2) * 4 + (lane >> 4)] = p;
        ed0[((size_t)batch * NN + i2) * 4 + (lane >> 4)] = qd;
      }
    }
  }
  // head MLP at t=0 on y0
#pragma unroll
  for (int d = 0; d < 64; ++d) wreg[d] = Wh[d * 64 + lane];
  float bb = b1v[lane], w2l = W2v[lane], b2s = b2v[0];
#pragma unroll
  for (int u2 = 0; u2 < 4; ++u2) {
    int i2l = wv * 4 + u2;
    if (i2l < cnt) {
      float o = 0.f;
#pragma unroll
      for (int dq = 0; dq < 16; ++dq) {
        int sl = (u2 << 4) + dq;
        o = fmaf(rdl(x4.x, sl), wreg[4 * dq + 0], o);
        o = fmaf(rdl(x4.y, sl), wreg[4 * dq + 1], o);
        o = fmaf(rdl(x4.z, sl), wreg[4 * dq + 2], o);
        o = fmaf(rdl(x4.w, sl), wreg[4 * dq + 3], o);
      }
      float z = tanhf(o + bb) * w2l;
#pragma unroll
      for (int mm = 1; mm < 64; mm <<= 1) z += __shfl_xor(z, mm, 64);
      if (lane == 0) out[((size_t)batch * (SEQ + 1) + 0) * NN + (n0 + i2l)] = z + b2s;
    }
  }
}

// ---- phase kernel. MODE 0: GAT-layer0 agg -> elu -> @W1 -> h2 + layer1 scores.
//      MODE 1+s: GAT-layer1 agg -> RK stage s -> @W0 -> h1 + layer0 scores (+head at s=3).
template <int MODE>
__global__ __launch_bounds__(512) void phase_k(
    const float* __restrict__ sin_, float* __restrict__ sout,
    const float* __restrict__ esin, const float* __restrict__ edin,
    float* __restrict__ esout, float* __restrict__ edout,
    const float* __restrict__ W, const float* __restrict__ asv,
    const float* __restrict__ adv, const int* __restrict__ deg,
    const unsigned short* __restrict__ cols, float* __restrict__ yy,
    float* __restrict__ acc, const float* __restrict__ Wh,
    const float* __restrict__ b1v, const float* __restrict__ W2v,
    const float* __restrict__ b2v, float* __restrict__ out, int tout) {
  __shared__ float slab[NN * SLDS];         // 88.4 KB
  __shared__ float sed[NN * 4];             // 5.2 KB
  __shared__ float wbuf[NPB][MAXDEG * 4];   // 26.9 KB
  __shared__ unsigned short jbuf[NPB][MAXDEG];  // 3.4 KB

  const int tid = threadIdx.x, lane = tid & 63, wv = tid >> 6;
  const int q = lane & 15, u = lane >> 4, head = q >> 2;
  const int batch = blockIdx.x & 15, chunk = blockIdx.x >> 4;
  const int n0 = chunk * NPB;
  const int cnt = (NN - n0) < NPB ? (NN - n0) : NPB;
  const float* sbase = sin_ + (size_t)batch * NN * DD;

  // stage slab (stride-68 depad) + ed scores
  for (int grp = wv; grp < 82; grp += 8) {
    int r = grp * 4 + u;
    if (r < NN) {
      float4 v = *(const float4*)(sbase + (size_t)r * DD + q * 4);
      *(float4*)&slab[r * SLDS + q * 4] = v;
    }
  }
  for (int idx = tid; idx < NN * 4; idx += 512) sed[idx] = edin[(size_t)batch * NN * 4 + idx];
  __syncthreads();

  const int il = wv * 4 + u;
  const int i = n0 + il;
  const bool active = il < cnt;
  int dg = 0;
  if (active) dg = min(deg[i], MAXDEG);

  // softmax weights (no max-subtraction: |e| is O(10), exp safe in fp32)
  if (active) {
    float esi = esin[((size_t)batch * NN + i) * 4 + (q & 3)];
    const unsigned short* cr = cols + (size_t)i * MAXDEG;
    for (int it = 0; it * 4 < dg; ++it) {
      int nbr = it * 4 + (q >> 2);
      if (nbr < dg) {
        int j = cr[nbr];
        float e = esi + sed[j * 4 + (q & 3)];
        e = fmaxf(e, NEG * e);
        wbuf[il][it * 16 + q] = __expf(e);
        if ((q & 3) == 0) jbuf[il][nbr] = (unsigned short)j;
      }
    }
  }
  __builtin_amdgcn_wave_barrier();  // order wave-local LDS writes before reads

  // aggregation: 4 nodes per wave, b128 slab gathers, branch-free w=0 padding
  int dgw = dg;
  dgw = max(dgw, __shfl_xor(dgw, 16, 64));
  dgw = max(dgw, __shfl_xor(dgw, 32, 64));
  const int ilc = active ? il : 0;
  float ax = 0.f, ay = 0.f, az = 0.f, aw = 0.f, den = 0.f;
  for (int jj = 0; jj < dgw; ++jj) {
    int jc = jj < dg ? jj : 0;
    int j = jbuf[ilc][jc];
    float w = wbuf[ilc][jc * 4 + head];
    if (!(active && jj < dg)) w = 0.f;
    j = j < NN ? j : 0;
    const float4 h = *(const float4*)&slab[j * SLDS + q * 4];
    den += w;
    ax = fmaf(w, h.x, ax);
    ay = fmaf(w, h.y, ay);
    az = fmaf(w, h.z, az);
    aw = fmaf(w, h.w, aw);
  }

  float4 x4 = {0.f, 0.f, 0.f, 0.f};
  if (active) {
    float inv = 1.f / den;
    ax *= inv; ay *= inv; az *= inv; aw *= inv;
    if (MODE == 0) {  // elu between GAT layers
      x4.x = ax > 0.f ? ax : __expf(ax) - 1.f;
      x4.y = ay > 0.f ? ay : __expf(ay) - 1.f;
      x4.z = az > 0.f ? az : __expf(az) - 1.f;
      x4.w = aw > 0.f ? aw : __expf(aw) - 1.f;
    } else {
      constexpr int s = MODE - 1;
      float4* accp = (float4*)(acc + ((size_t)batch * NN + i) * DD + q * 4);
      float4* yyp = (float4*)(yy + ((size_t)batch * NN + i) * DD + q * 4);
      float4 yv = *yyp;
      if (s == 0) {
        float4 t; t.x = ax; t.y = ay; t.z = az; t.w = aw;
        *accp = t;
        x4.x = yv.x + 0.5f * DT * ax; x4.y = yv.y + 0.5f * DT * ay;
        x4.z = yv.z + 0.5f * DT * az; x4.w = yv.w + 0.5f * DT * aw;
      } else if (s == 1 || s == 2) {
        float4 t = *accp;
        t.x += 2.f * ax; t.y += 2.f * ay; t.z += 2.f * az; t.w += 2.f * aw;
        *accp = t;
        const float c = (s == 1) ? 0.5f * DT : DT;
        x4.x = yv.x + c * ax; x4.y = yv.y + c * ay;
        x4.z = yv.z + c * az; x4.w = yv.w + c * aw;
      } else {
        float4 t = *accp;
        x4.x = yv.x + (DT / 6.f) * (t.x + ax);
        x4.y = yv.y + (DT / 6.f) * (t.y + ay);
        x4.z = yv.z + (DT / 6.f) * (t.z + az);
        x4.w = yv.w + (DT / 6.f) * (t.w + aw);
        *yyp = x4;  // y_{t+1}
      }
    }
  }

  // matvec: weight column in 64 VGPRs, x broadcast via v_readlane (VALU, not LDS pipe)
  float wreg[64];
#pragma unroll
  for (int d = 0; d < 64; ++d) wreg[d] = W[d * 64 + lane];
  float asl = asv[lane], adl = adv[lane];
#pragma unroll
  for (int u2 = 0; u2 < 4; ++u2) {
    int i2l = wv * 4 + u2;
    if (i2l < cnt) {
      int i2 = n0 + i2l;
      float o = 0.f;
#pragma unroll
      for (int dq = 0; dq < 16; ++dq) {
        int sl = (u2 << 4) + dq;
        o = fmaf(rdl(x4.x, sl), wreg[4 * dq + 0], o);
        o = fmaf(rdl(x4.y, sl), wreg[4 * dq + 1], o);
        o = fmaf(rdl(x4.z, sl), wreg[4 * dq + 2], o);
        o = fmaf(rdl(x4.w, sl), wreg[4 * dq + 3], o);
      }
      sout[((size_t)batch * NN + i2) * DD + lane] = o;
      float p = o * asl, qd = o * adl;
#pragma unroll
      for (int mm = 1; mm < 16; mm <<= 1) {
        p += __shfl_xor(p, mm, 64);
        qd += __shfl_xor(qd, mm, 64);
      }
      if ((lane & 15) == 0) {
        esout[((size_t)batch * NN + i2) * 4 + (lane >> 4)] = p;
        edout[((size_t)batch * NN + i2) * 4 + (lane >> 4)] = qd;
      }
    }
  }

  if (MODE == 4) {  // head MLP on fresh y_{t+1} (x4 holds it)
#pragma unroll
    for (int d = 0; d < 64; ++d) wreg[d] = Wh[d * 64 + lane];
    float bb = b1v[lane], w2l = W2v[lane], b2s = b2v[0];
#pragma unroll
    for (int u2 = 0; u2 < 4; ++u2) {
      int i2l = wv * 4 + u2;
      if (i2l < cnt) {
        float o = 0.f;
#pragma unroll
        for (int dq = 0; dq < 16; ++dq) {
          int sl = (u2 << 4) + dq;
          o = fmaf(rdl(x4.x, sl), wreg[4 * dq + 0], o);
          o = fmaf(rdl(x4.y, sl), wreg[4 * dq + 1], o);
          o = fmaf(rdl(x4.z, sl), wreg[4 * dq + 2], o);
          o = fmaf(rdl(x4.w, sl), wreg[4 * dq + 3], o);
        }
        float z = tanhf(o + bb) * w2l;
#pragma unroll
        for (int mm = 1; mm < 64; mm <<= 1) z += __shfl_xor(z, mm, 64);
        if (lane == 0) out[((size_t)batch * (SEQ + 1) + tout) * NN + (n0 + i2l)] = z + b2s;
      }
    }
  }
}

extern "C" void kernel_launch(void* const* d_in, const int* in_sizes, int n_in,
                              void* d_out, int out_size, void* d_ws, size_t ws_size,
                              hipStream_t stream) {
  const float* y0 = (const float*)d_in[0];
  const float* graph = (const float*)d_in[1];
  const float* Wg = (const float*)d_in[2];
  const float* a_src = (const float*)d_in[3];
  const float* a_dst = (const float*)d_in[4];
  const float* W1 = (const float*)d_in[5];
  const float* b1 = (const float*)d_in[6];
  const float* W2 = (const float*)d_in[7];
  const float* b2 = (const float*)d_in[8];
  float* out = (float*)d_out;

  char* ws = (char*)d_ws;
  size_t off = 0;
  auto take = [&](size_t bytes) -> char* {
    char* p = ws + off;
    off += (bytes + 255) & ~size_t(255);
    return p;
  };
  unsigned short* cols = (unsigned short*)take((size_t)NN * MAXDEG * sizeof(unsigned short));
  int* deg = (int*)take(NN * sizeof(int));
  float* hA = (float*)take((size_t)BB * NN * DD * sizeof(float));
  float* hB = (float*)take((size_t)BB * NN * DD * sizeof(float));
  float* es0 = (float*)take((size_t)BB * NN * 4 * sizeof(float));
  float* ed0 = (float*)take((size_t)BB * NN * 4 * sizeof(float));
  float* es1 = (float*)take((size_t)BB * NN * 4 * sizeof(float));
  float* ed1 = (float*)take((size_t)BB * NN * 4 * sizeof(float));
  float* yy = (float*)take((size_t)BB * NN * DD * sizeof(float));
  float* acc = (float*)take((size_t)BB * NN * DD * sizeof(float));
  if (off > ws_size) return;  // loud failure: output stays poisoned

  const float* W0g = Wg;
  const float* W1g = Wg + 64 * 64;
  const dim3 G(256), T(512);

  adj_k<<<dim3(NN), dim3(64), 0, stream>>>(graph, deg, cols);
  init_k<<<G, T, 0, stream>>>(y0, W0g, a_src, a_dst, W1, b1, W2, b2, yy, hA, es0, ed0, out);

  for (int t = 0; t < SEQ; ++t) {
    phase_k<0><<<G, T, 0, stream>>>(hA, hB, es0, ed0, es1, ed1, W1g, a_src + 64, a_dst + 64,
                                    deg, cols, yy, acc, W1, b1, W2, b2, out, 0);
    phase_k<1><<<G, T, 0, stream>>>(hB, hA, es1, ed1, es0, ed0, W0g, a_src, a_dst,
                                    deg, cols, yy, acc, W1, b1, W2, b2, out, 0);
    phase_k<0><<<G, T, 0, stream>>>(hA, hB, es0, ed0, es1, ed1, W1g, a_src + 64, a_dst + 64,
                                    deg, cols, yy, acc, W1, b1, W2, b2, out, 0);
    phase_k<2><<<G, T, 0, stream>>>(hB, hA, es1, ed1, es0, ed0, W0g, a_src, a_dst,
                                    deg, cols, yy, acc, W1, b1, W2, b2, out, 0);
    phase_k<0><<<G, T, 0, stream>>>(hA, hB, es0, ed0, es1, ed1, W1g, a_src + 64, a_dst + 64,
                                    deg, cols, yy, acc, W1, b1, W2, b2, out, 0);
    phase_k<3><<<G, T, 0, stream>>>(hB, hA, es1, ed1, es0, ed0, W0g, a_src, a_dst,
                                    deg, cols, yy, acc, W1, b1, W2, b2, out, 0);
    phase_k<0><<<G, T, 0, stream>>>(hA, hB, es0, ed0, es1, ed1, W1g, a_src + 64, a_dst + 64,
                                    deg, cols, yy, acc, W1, b1, W2, b2, out, 0);
    phase_k<4><<<G, T, 0, stream>>>(hB, hA, es1, ed1, es0, ed0, W0g, a_src, a_dst,
                                    deg, cols, yy, acc, W1, b1, W2, b2, out, t + 1);
  }
}